// Round 17
// baseline (31.419 us; speedup 1.0000x reference)
//
#include <hip/hip_runtime.h>
#include <hip/hip_bf16.h>

#define LEAKY 0.2f
#define B_TOT 8192
#define N_TOT 2048
#define D_TOT 128
#define BM 32

typedef float f32x16 __attribute__((ext_vector_type(16)));
typedef short bf16x8 __attribute__((ext_vector_type(8)));
typedef unsigned short u16x8 __attribute__((ext_vector_type(8)));

static __device__ __forceinline__ unsigned short f2bf(float x) {
    return __builtin_bit_cast(unsigned short, __float2bfloat16(x));
}

// ---------------- prep: q-dots + 32x32x16-fragment-ordered bf16 DnT (R16 verbatim) ----------------
__global__ __launch_bounds__(256) void prep_kernel(const float* __restrict__ disease,
                                                   const float* __restrict__ ak,
                                                   float* __restrict__ q,
                                                   uint4* __restrict__ DnTf) {
    __shared__ float tile[32][129];   // +1 pad
    __shared__ float a_s[D_TOT];
    const int tid = threadIdx.x;
    const int b = blockIdx.x;
    const int r0 = b * 32;

    if (tid < D_TOT) a_s[tid] = ak[D_TOT + tid];
    #pragma unroll
    for (int t = 0; t < 4; ++t) {
        int idx = tid + t * 256;          // 0..1023 float4 slots
        int row = idx >> 5;
        int cv = (idx & 31) * 4;
        float4 v = *(const float4*)(disease + (size_t)(r0 + row) * D_TOT + cv);
        tile[row][cv] = v.x; tile[row][cv + 1] = v.y;
        tile[row][cv + 2] = v.z; tile[row][cv + 3] = v.w;
    }
    __syncthreads();

    const int wave = tid >> 6, lane = tid & 63;
    #pragma unroll
    for (int rr = 0; rr < 8; ++rr) {
        int r = wave * 8 + rr;
        float s = tile[r][lane] * a_s[lane] + tile[r][lane + 64] * a_s[lane + 64];
        #pragma unroll
        for (int off = 32; off; off >>= 1) s += __shfl_xor(s, off);
        if (lane == 0) q[r0 + r] = s;
    }

    #pragma unroll
    for (int h = 0; h < 2; ++h) {
        const int ci = tid + h * 256;     // 0..511
        const int f  = ci >> 6;           // fragment 0..7 = lt*4+ct
        const int ln = ci & 63;
        const int lt = f >> 2, ct = f & 3;
        const int g  = ln >> 5, c = ln & 31;
        const int rb = lt * 16 + g * 8;
        unsigned u[4];
        #pragma unroll
        for (int jj = 0; jj < 4; ++jj) {
            unsigned lo = f2bf(tile[rb + 2 * jj][ct * 32 + c]);
            unsigned hi = f2bf(tile[rb + 2 * jj + 1][ct * 32 + c]);
            u[jj] = lo | (hi << 16);
        }
        DnTf[((size_t)(2 * b + lt) * 4 + ct) * 64 + ln] = make_uint4(u[0], u[1], u[2], u[3]);
    }
}

// ---------------- main: 32x32x16 MFMA, BM=32, 512-thread blocks, 2 blocks/CU ----------------
// 256 blocks x 512 threads. 8 waves = cw(2 col-halves) x kq(4 K-quarters).
// LDS ~66KB -> 2 co-resident blocks overlap each other's barrier drains.
__global__ __launch_bounds__(512, 4) void gat_mfma32(const float* __restrict__ patient,
                                                     const float* __restrict__ ak,
                                                     const float* __restrict__ q,
                                                     const uint4* __restrict__ DnTf,
                                                     float* __restrict__ out) {
    __shared__ __align__(16) float eq1_s[N_TOT];
    __shared__ __align__(16) float eq2_s[N_TOT];
    __shared__ float red_s[3][2][2048];   // [kq-1][cw][row_local*64 + t*32 + c]
    __shared__ float a_s[D_TOT];
    __shared__ float p_s[BM], E1_s[BM], E2_s[BM], S_s[BM];
    __shared__ float red8[8];

    const int tid  = threadIdx.x;
    const int wave = tid >> 6;        // 0..7
    const int lane = tid & 63;
    const int b0   = blockIdx.x * BM;

    if (tid < D_TOT) a_s[tid] = ak[tid];
    __syncthreads();

    // eq1/eq2 + qmax partials (4 elements per thread)
    float mx = -1e30f;
    for (int i = tid; i < N_TOT; i += 512) {
        float qq = q[i];
        eq1_s[i] = __expf(qq);
        eq2_s[i] = __expf(LEAKY * qq);
        mx = fmaxf(mx, qq);
    }
    #pragma unroll
    for (int off = 32; off; off >>= 1) mx = fmaxf(mx, __shfl_xor(mx, off));
    if (lane == 0) red8[wave] = mx;

    // p-dots: wave w -> rows 4w..4w+3
    #pragma unroll
    for (int rr = 0; rr < 4; ++rr) {
        const int row = wave * 4 + rr;
        const float* pr = patient + (size_t)(b0 + row) * D_TOT;
        float s = pr[lane] * a_s[lane] + pr[lane + 64] * a_s[lane + 64];
        #pragma unroll
        for (int off = 32; off; off >>= 1) s += __shfl_xor(s, off);
        if (lane == 0) p_s[row] = s;
    }
    __syncthreads();

    if (tid < BM) {
        float qmax = red8[0];
        #pragma unroll
        for (int i = 1; i < 8; ++i) qmax = fmaxf(qmax, red8[i]);
        const float pv = p_s[tid];
        const float xm = pv + qmax;
        const float m = fmaxf(xm, LEAKY * xm);    // row max (leaky monotonic)
        E1_s[tid] = __expf(pv - m);
        E2_s[tid] = __expf(LEAKY * pv - m);
    }
    __syncthreads();

    // S per row (wave w -> rows 4w..4w+3): S = sum_n max(E1*eq1, E2*eq2)  (exact)
    #pragma unroll
    for (int rr = 0; rr < 4; ++rr) {
        const int row = wave * 4 + rr;
        const float E1 = E1_s[row], E2 = E2_s[row];
        float s = 0.f;
        for (int n = lane; n < N_TOT; n += 64)
            s += fmaxf(E1 * eq1_s[n], E2 * eq2_s[n]);
        #pragma unroll
        for (int off = 32; off; off >>= 1) s += __shfl_xor(s, off);
        if (lane == 0) S_s[row] = s;
    }
    __syncthreads();

    // ---- barrier-free 32x32x16 MFMA K-loop ----
    const int c31 = lane & 31;        // A row / B,D col
    const int g   = lane >> 5;        // k-group (0/1)
    const int cw  = wave & 1;         // 64-col half
    const int kq  = wave >> 1;        // K quarter (0..3), 32 k-tiles each

    const float E1A = E1_s[c31], E2A = E2_s[c31];
    const uint4* fbase = DnTf + (size_t)(cw * 2) * 64 + lane;   // + kt*256 (+64 for t=1)

    f32x16 acc0{}, acc1{};

    for (int kt = kq * 32; kt < kq * 32 + 32; ++kt) {
        const uint4* fp = fbase + (size_t)kt * 256;
        const uint4 bv0 = fp[0];
        const uint4 bv1 = fp[64];

        const int gk = kt * 16 + g * 8;
        u16x8 aw;
        {
            const float4 e1 = *(const float4*)&eq1_s[gk];
            const float4 e2 = *(const float4*)&eq2_s[gk];
            aw[0] = f2bf(fmaxf(E1A * e1.x, E2A * e2.x));
            aw[1] = f2bf(fmaxf(E1A * e1.y, E2A * e2.y));
            aw[2] = f2bf(fmaxf(E1A * e1.z, E2A * e2.z));
            aw[3] = f2bf(fmaxf(E1A * e1.w, E2A * e2.w));
        }
        {
            const float4 e1 = *(const float4*)&eq1_s[gk + 4];
            const float4 e2 = *(const float4*)&eq2_s[gk + 4];
            aw[4] = f2bf(fmaxf(E1A * e1.x, E2A * e2.x));
            aw[5] = f2bf(fmaxf(E1A * e1.y, E2A * e2.y));
            aw[6] = f2bf(fmaxf(E1A * e1.z, E2A * e2.z));
            aw[7] = f2bf(fmaxf(E1A * e1.w, E2A * e2.w));
        }
        const bf16x8 a0 = __builtin_bit_cast(bf16x8, aw);

        acc0 = __builtin_amdgcn_mfma_f32_32x32x16_bf16(a0, __builtin_bit_cast(bf16x8, bv0), acc0, 0, 0, 0);
        acc1 = __builtin_amdgcn_mfma_f32_32x32x16_bf16(a0, __builtin_bit_cast(bf16x8, bv1), acc1, 0, 0, 0);
    }

    // ---- split-K reduction ----
    // C/D map (HW-verified): col = lane&31, row_local = (reg&3) + 8*(reg>>2) + 4*(lane>>5)
    __syncthreads();
    if (kq > 0) {
        float* rb = &red_s[kq - 1][cw][0];
        #pragma unroll
        for (int rg = 0; rg < 16; ++rg) {
            const int rl = (rg & 3) + 8 * (rg >> 2) + 4 * g;
            rb[rl * 64 + c31]      = acc0[rg];
            rb[rl * 64 + 32 + c31] = acc1[rg];
        }
    }
    __syncthreads();
    if (kq == 0) {
        #pragma unroll
        for (int rg = 0; rg < 16; ++rg) {
            const int rl = (rg & 3) + 8 * (rg >> 2) + 4 * g;
            float s0 = acc0[rg], s1 = acc1[rg];
            #pragma unroll
            for (int j = 0; j < 3; ++j) {
                s0 += red_s[j][cw][rl * 64 + c31];
                s1 += red_s[j][cw][rl * 64 + 32 + c31];
            }
            const float inv = 1.0f / S_s[rl];
            const int row = b0 + rl;
            const int colA = cw * 64 + c31;
            const int colB = colA + 32;
            out[(size_t)row * D_TOT + colA] = patient[(size_t)row * D_TOT + colA] + s0 * inv;
            out[(size_t)row * D_TOT + colB] = patient[(size_t)row * D_TOT + colB] + s1 * inv;
        }
    }
}

// ---------------- tiny fallback (round-1, known-passing) ----------------
__global__ __launch_bounds__(256) void pq_fb(const float* __restrict__ patient,
                                             const float* __restrict__ disease,
                                             const float* __restrict__ ak,
                                             float* __restrict__ p,
                                             float* __restrict__ q) {
    int gid  = blockIdx.x * blockDim.x + threadIdx.x;
    int wid  = gid >> 6;
    int lane = gid & 63;
    const float* src;
    const float* a;
    float* dst;
    if (wid < B_TOT) {
        src = patient + (size_t)wid * D_TOT; a = ak; dst = p + wid;
    } else {
        src = disease + (size_t)(wid - B_TOT) * D_TOT; a = ak + D_TOT; dst = q + (wid - B_TOT);
    }
    float s = src[lane] * a[lane] + src[lane + 64] * a[lane + 64];
    #pragma unroll
    for (int off = 32; off; off >>= 1) s += __shfl_xor(s, off);
    if (lane == 0) *dst = s;
}

#define FBP 16
#define FNT 256
__global__ __launch_bounds__(256) void gat_fb(const float* __restrict__ patient,
                                              const float* __restrict__ disease,
                                              const float* __restrict__ p,
                                              const float* __restrict__ q,
                                              float* __restrict__ out) {
    __shared__ float q_s[N_TOT];
    __shared__ float w_s[FBP][FNT];
    __shared__ float m_s[FBP], S_s[FBP], pp_s[FBP];
    const int tid = threadIdx.x;
    const int b0  = blockIdx.x * FBP;
    for (int i = tid; i < N_TOT; i += 256) q_s[i] = q[i];
    if (tid < FBP) pp_s[tid] = p[b0 + tid];
    __syncthreads();
    const int wave = tid >> 6, lane = tid & 63;
    for (int pi = wave * 4; pi < wave * 4 + 4; ++pi) {
        float pp = pp_s[pi];
        float mx = -1e30f;
        for (int n = lane; n < N_TOT; n += 64) {
            float x = pp + q_s[n]; x = x > 0.0f ? x : LEAKY * x; mx = fmaxf(mx, x);
        }
        #pragma unroll
        for (int off = 32; off; off >>= 1) mx = fmaxf(mx, __shfl_xor(mx, off));
        float sum = 0.0f;
        for (int n = lane; n < N_TOT; n += 64) {
            float x = pp + q_s[n]; x = x > 0.0f ? x : LEAKY * x; sum += __expf(x - mx);
        }
        #pragma unroll
        for (int off = 32; off; off >>= 1) sum += __shfl_xor(sum, off);
        if (lane == 0) { m_s[pi] = mx; S_s[pi] = sum; }
    }
    __syncthreads();
    const int d2 = tid & 31;
    const int pg = tid >> 5;
    const int p0 = 2 * pg, p1 = 2 * pg + 1;
    float4 acc0 = make_float4(0.f, 0.f, 0.f, 0.f);
    float4 acc1 = make_float4(0.f, 0.f, 0.f, 0.f);
    for (int n0 = 0; n0 < N_TOT; n0 += FNT) {
        __syncthreads();
        for (int i = tid; i < FBP * FNT; i += 256) {
            int pi = i >> 8;
            int nt = i & (FNT - 1);
            float x = pp_s[pi] + q_s[n0 + nt];
            x = x > 0.0f ? x : LEAKY * x;
            w_s[pi][nt] = __expf(x - m_s[pi]);
        }
        __syncthreads();
        const float* drow = disease + (size_t)n0 * D_TOT + d2 * 4;
        #pragma unroll 4
        for (int nt = 0; nt < FNT; ++nt) {
            float4 dv = *reinterpret_cast<const float4*>(drow + (size_t)nt * D_TOT);
            float w0 = w_s[p0][nt];
            float w1 = w_s[p1][nt];
            acc0.x += w0 * dv.x; acc0.y += w0 * dv.y; acc0.z += w0 * dv.z; acc0.w += w0 * dv.w;
            acc1.x += w1 * dv.x; acc1.y += w1 * dv.y; acc1.z += w1 * dv.z; acc1.w += w1 * dv.w;
        }
    }
    const float inv0 = 1.0f / S_s[p0];
    const float inv1 = 1.0f / S_s[p1];
    {
        size_t off = (size_t)(b0 + p0) * D_TOT + d2 * 4;
        float4 pf = *reinterpret_cast<const float4*>(patient + off);
        float4 o;
        o.x = pf.x + acc0.x * inv0; o.y = pf.y + acc0.y * inv0;
        o.z = pf.z + acc0.z * inv0; o.w = pf.w + acc0.w * inv0;
        *reinterpret_cast<float4*>(reinterpret_cast<float*>(out) + off) = o;
    }
    {
        size_t off = (size_t)(b0 + p1) * D_TOT + d2 * 4;
        float4 pf = *reinterpret_cast<const float4*>(patient + off);
        float4 o;
        o.x = pf.x + acc1.x * inv1; o.y = pf.y + acc1.y * inv1;
        o.z = pf.z + acc1.z * inv1; o.w = pf.w + acc1.w * inv1;
        *reinterpret_cast<float4*>(reinterpret_cast<float*>(out) + off) = o;
    }
}

extern "C" void kernel_launch(void* const* d_in, const int* in_sizes, int n_in,
                              void* d_out, int out_size, void* d_ws, size_t ws_size,
                              hipStream_t stream) {
    const float* patient = (const float*)d_in[0];   // 8192 x 128
    const float* disease = (const float*)d_in[1];   // 2048 x 128
    const float* ak      = (const float*)d_in[2];   // 256
    float* out = (float*)d_out;

    const size_t need_fast = (size_t)512 * 1024 + 8192;   // DnTf (512KB) + q (8KB)
    if (ws_size >= need_fast) {
        uint4* DnTf = (uint4*)d_ws;                          // 128 kt x 4 ct x 64 uint4 = 512KB
        float* q    = (float*)((char*)d_ws + 512 * 1024);    // 2048 f32
        prep_kernel<<<N_TOT / 32, 256, 0, stream>>>(disease, ak, q, DnTf);
        gat_mfma32<<<B_TOT / BM, 512, 0, stream>>>(patient, ak, q, DnTf, out);
    } else {
        float* p = (float*)d_ws;          // 8192 f32
        float* q = p + B_TOT;             // 2048 f32
        pq_fb<<<(B_TOT + N_TOT) / 4, 256, 0, stream>>>(patient, disease, ak, p, q);
        gat_fb<<<B_TOT / FBP, 256, 0, stream>>>(patient, disease, p, q, out);
    }
}

// Round 18
// 26.186 us; speedup vs baseline: 1.1998x; 1.1998x over previous
//
#include <hip/hip_runtime.h>
#include <hip/hip_bf16.h>

#define LEAKY 0.2f
#define B_TOT 8192
#define N_TOT 2048
#define D_TOT 128
#define BM 32

typedef float f32x16 __attribute__((ext_vector_type(16)));
typedef short bf16x8 __attribute__((ext_vector_type(8)));
typedef unsigned short u16x8 __attribute__((ext_vector_type(8)));

static __device__ __forceinline__ unsigned short f2bf(float x) {
    return __builtin_bit_cast(unsigned short, __float2bfloat16(x));
}

// ---------------- prep: q-dots + 32x32x16-fragment-ordered bf16 DnT ----------------
// Block b: disease rows [b*32, b*32+32) = k-tiles 2b, 2b+1 (16 k each).
// Fragment (kt, ct): uint4 at (kt*4+ct)*64+lane holds B[k=kt*16+(lane>>5)*8+j][col=ct*32+(lane&31)].
__global__ __launch_bounds__(256) void prep_kernel(const float* __restrict__ disease,
                                                   const float* __restrict__ ak,
                                                   float* __restrict__ q,
                                                   uint4* __restrict__ DnTf) {
    __shared__ float tile[32][129];   // +1 pad
    __shared__ float a_s[D_TOT];
    const int tid = threadIdx.x;
    const int b = blockIdx.x;
    const int r0 = b * 32;

    if (tid < D_TOT) a_s[tid] = ak[D_TOT + tid];
    #pragma unroll
    for (int t = 0; t < 4; ++t) {
        int idx = tid + t * 256;          // 0..1023 float4 slots
        int row = idx >> 5;
        int cv = (idx & 31) * 4;
        float4 v = *(const float4*)(disease + (size_t)(r0 + row) * D_TOT + cv);
        tile[row][cv] = v.x; tile[row][cv + 1] = v.y;
        tile[row][cv + 2] = v.z; tile[row][cv + 3] = v.w;
    }
    __syncthreads();

    const int wave = tid >> 6, lane = tid & 63;
    #pragma unroll
    for (int rr = 0; rr < 8; ++rr) {
        int r = wave * 8 + rr;
        float s = tile[r][lane] * a_s[lane] + tile[r][lane + 64] * a_s[lane + 64];
        #pragma unroll
        for (int off = 32; off; off >>= 1) s += __shfl_xor(s, off);
        if (lane == 0) q[r0 + r] = s;
    }

    #pragma unroll
    for (int h = 0; h < 2; ++h) {
        const int ci = tid + h * 256;     // 0..511
        const int f  = ci >> 6;           // fragment 0..7 = lt*4+ct
        const int ln = ci & 63;
        const int lt = f >> 2, ct = f & 3;
        const int g  = ln >> 5, c = ln & 31;
        const int rb = lt * 16 + g * 8;
        unsigned u[4];
        #pragma unroll
        for (int jj = 0; jj < 4; ++jj) {
            unsigned lo = f2bf(tile[rb + 2 * jj][ct * 32 + c]);
            unsigned hi = f2bf(tile[rb + 2 * jj + 1][ct * 32 + c]);
            u[jj] = lo | (hi << 16);
        }
        DnTf[((size_t)(2 * b + lt) * 4 + ct) * 64 + ln] = make_uint4(u[0], u[1], u[2], u[3]);
    }
}

// ---------------- main: 32x32x16 MFMA, BM=32 (R16 proven best) ----------------
// 256 blocks x 1024 threads (1 block/CU). 16 waves = cw(2 col-halves) x kq(8).
__global__ __launch_bounds__(1024, 4) void gat_mfma32(const float* __restrict__ patient,
                                                      const float* __restrict__ ak,
                                                      const float* __restrict__ q,
                                                      const uint4* __restrict__ DnTf,
                                                      float* __restrict__ out) {
    __shared__ __align__(16) float eq1_s[N_TOT];
    __shared__ __align__(16) float eq2_s[N_TOT];
    __shared__ float red_s[7][2][2048];   // [kq-1][cw][row_local*64 + t*32 + c]
    __shared__ float a_s[D_TOT];
    __shared__ float p_s[BM], E1_s[BM], E2_s[BM], S_s[BM];
    __shared__ float red16[16];

    const int tid  = threadIdx.x;
    const int wave = tid >> 6;
    const int lane = tid & 63;
    const int b0   = blockIdx.x * BM;

    if (tid < D_TOT) a_s[tid] = ak[tid];
    __syncthreads();

    // eq1/eq2 + qmax partials
    float mx = -1e30f;
    for (int i = tid; i < N_TOT; i += 1024) {
        float qq = q[i];
        eq1_s[i] = __expf(qq);
        eq2_s[i] = __expf(LEAKY * qq);
        mx = fmaxf(mx, qq);
    }
    #pragma unroll
    for (int off = 32; off; off >>= 1) mx = fmaxf(mx, __shfl_xor(mx, off));
    if (lane == 0) red16[wave] = mx;

    // p-dots: wave w -> rows 2w, 2w+1
    #pragma unroll
    for (int rr = 0; rr < 2; ++rr) {
        const int row = wave * 2 + rr;
        const float* pr = patient + (size_t)(b0 + row) * D_TOT;
        float s = pr[lane] * a_s[lane] + pr[lane + 64] * a_s[lane + 64];
        #pragma unroll
        for (int off = 32; off; off >>= 1) s += __shfl_xor(s, off);
        if (lane == 0) p_s[row] = s;
    }
    __syncthreads();

    if (tid < BM) {
        float qmax = red16[0];
        #pragma unroll
        for (int i = 1; i < 16; ++i) qmax = fmaxf(qmax, red16[i]);
        const float pv = p_s[tid];
        const float xm = pv + qmax;
        const float m = fmaxf(xm, LEAKY * xm);    // row max (leaky monotonic)
        E1_s[tid] = __expf(pv - m);
        E2_s[tid] = __expf(LEAKY * pv - m);
    }
    __syncthreads();

    // S per row (wave w -> rows 2w, 2w+1): S = sum_n max(E1*eq1, E2*eq2)  (exact)
    #pragma unroll
    for (int rr = 0; rr < 2; ++rr) {
        const int row = wave * 2 + rr;
        const float E1 = E1_s[row], E2 = E2_s[row];
        float s = 0.f;
        for (int n = lane; n < N_TOT; n += 64)
            s += fmaxf(E1 * eq1_s[n], E2 * eq2_s[n]);
        #pragma unroll
        for (int off = 32; off; off >>= 1) s += __shfl_xor(s, off);
        if (lane == 0) S_s[row] = s;
    }
    __syncthreads();

    // ---- barrier-free 32x32x16 MFMA K-loop ----
    const int c31 = lane & 31;        // A row / B,D col
    const int g   = lane >> 5;        // k-group (0/1)
    const int cw  = wave & 1;         // 64-col half
    const int kq  = wave >> 1;        // K eighth (0..7), 16 k-tiles each

    const float E1A = E1_s[c31], E2A = E2_s[c31];
    const uint4* fbase = DnTf + (size_t)(cw * 2) * 64 + lane;   // + kt*256 (+64 for t=1)

    f32x16 acc0{}, acc1{};

    for (int kt = kq * 16; kt < kq * 16 + 16; ++kt) {
        const uint4* fp = fbase + (size_t)kt * 256;
        const uint4 bv0 = fp[0];
        const uint4 bv1 = fp[64];

        const int gk = kt * 16 + g * 8;
        u16x8 aw;
        {
            const float4 e1 = *(const float4*)&eq1_s[gk];
            const float4 e2 = *(const float4*)&eq2_s[gk];
            aw[0] = f2bf(fmaxf(E1A * e1.x, E2A * e2.x));
            aw[1] = f2bf(fmaxf(E1A * e1.y, E2A * e2.y));
            aw[2] = f2bf(fmaxf(E1A * e1.z, E2A * e2.z));
            aw[3] = f2bf(fmaxf(E1A * e1.w, E2A * e2.w));
        }
        {
            const float4 e1 = *(const float4*)&eq1_s[gk + 4];
            const float4 e2 = *(const float4*)&eq2_s[gk + 4];
            aw[4] = f2bf(fmaxf(E1A * e1.x, E2A * e2.x));
            aw[5] = f2bf(fmaxf(E1A * e1.y, E2A * e2.y));
            aw[6] = f2bf(fmaxf(E1A * e1.z, E2A * e2.z));
            aw[7] = f2bf(fmaxf(E1A * e1.w, E2A * e2.w));
        }
        const bf16x8 a0 = __builtin_bit_cast(bf16x8, aw);

        acc0 = __builtin_amdgcn_mfma_f32_32x32x16_bf16(a0, __builtin_bit_cast(bf16x8, bv0), acc0, 0, 0, 0);
        acc1 = __builtin_amdgcn_mfma_f32_32x32x16_bf16(a0, __builtin_bit_cast(bf16x8, bv1), acc1, 0, 0, 0);
    }

    // ---- split-K reduction ----
    // C/D map (HW-verified): col = lane&31, row_local = (reg&3) + 8*(reg>>2) + 4*(lane>>5)
    __syncthreads();
    if (kq > 0) {
        float* rb = &red_s[kq - 1][cw][0];
        #pragma unroll
        for (int rg = 0; rg < 16; ++rg) {
            const int rl = (rg & 3) + 8 * (rg >> 2) + 4 * g;
            rb[rl * 64 + c31]      = acc0[rg];
            rb[rl * 64 + 32 + c31] = acc1[rg];
        }
    }
    __syncthreads();
    if (kq == 0) {
        #pragma unroll
        for (int rg = 0; rg < 16; ++rg) {
            const int rl = (rg & 3) + 8 * (rg >> 2) + 4 * g;
            float s0 = acc0[rg], s1 = acc1[rg];
            #pragma unroll
            for (int j = 0; j < 7; ++j) {
                s0 += red_s[j][cw][rl * 64 + c31];
                s1 += red_s[j][cw][rl * 64 + 32 + c31];
            }
            const float inv = 1.0f / S_s[rl];
            const int row = b0 + rl;
            const int colA = cw * 64 + c31;
            const int colB = colA + 32;
            out[(size_t)row * D_TOT + colA] = patient[(size_t)row * D_TOT + colA] + s0 * inv;
            out[(size_t)row * D_TOT + colB] = patient[(size_t)row * D_TOT + colB] + s1 * inv;
        }
    }
}

// ---------------- tiny fallback (round-1, known-passing) ----------------
__global__ __launch_bounds__(256) void pq_fb(const float* __restrict__ patient,
                                             const float* __restrict__ disease,
                                             const float* __restrict__ ak,
                                             float* __restrict__ p,
                                             float* __restrict__ q) {
    int gid  = blockIdx.x * blockDim.x + threadIdx.x;
    int wid  = gid >> 6;
    int lane = gid & 63;
    const float* src;
    const float* a;
    float* dst;
    if (wid < B_TOT) {
        src = patient + (size_t)wid * D_TOT; a = ak; dst = p + wid;
    } else {
        src = disease + (size_t)(wid - B_TOT) * D_TOT; a = ak + D_TOT; dst = q + (wid - B_TOT);
    }
    float s = src[lane] * a[lane] + src[lane + 64] * a[lane + 64];
    #pragma unroll
    for (int off = 32; off; off >>= 1) s += __shfl_xor(s, off);
    if (lane == 0) *dst = s;
}

#define FBP 16
#define FNT 256
__global__ __launch_bounds__(256) void gat_fb(const float* __restrict__ patient,
                                              const float* __restrict__ disease,
                                              const float* __restrict__ p,
                                              const float* __restrict__ q,
                                              float* __restrict__ out) {
    __shared__ float q_s[N_TOT];
    __shared__ float w_s[FBP][FNT];
    __shared__ float m_s[FBP], S_s[FBP], pp_s[FBP];
    const int tid = threadIdx.x;
    const int b0  = blockIdx.x * FBP;
    for (int i = tid; i < N_TOT; i += 256) q_s[i] = q[i];
    if (tid < FBP) pp_s[tid] = p[b0 + tid];
    __syncthreads();
    const int wave = tid >> 6, lane = tid & 63;
    for (int pi = wave * 4; pi < wave * 4 + 4; ++pi) {
        float pp = pp_s[pi];
        float mx = -1e30f;
        for (int n = lane; n < N_TOT; n += 64) {
            float x = pp + q_s[n]; x = x > 0.0f ? x : LEAKY * x; mx = fmaxf(mx, x);
        }
        #pragma unroll
        for (int off = 32; off; off >>= 1) mx = fmaxf(mx, __shfl_xor(mx, off));
        float sum = 0.0f;
        for (int n = lane; n < N_TOT; n += 64) {
            float x = pp + q_s[n]; x = x > 0.0f ? x : LEAKY * x; sum += __expf(x - mx);
        }
        #pragma unroll
        for (int off = 32; off; off >>= 1) sum += __shfl_xor(sum, off);
        if (lane == 0) { m_s[pi] = mx; S_s[pi] = sum; }
    }
    __syncthreads();
    const int d2 = tid & 31;
    const int pg = tid >> 5;
    const int p0 = 2 * pg, p1 = 2 * pg + 1;
    float4 acc0 = make_float4(0.f, 0.f, 0.f, 0.f);
    float4 acc1 = make_float4(0.f, 0.f, 0.f, 0.f);
    for (int n0 = 0; n0 < N_TOT; n0 += FNT) {
        __syncthreads();
        for (int i = tid; i < FBP * FNT; i += 256) {
            int pi = i >> 8;
            int nt = i & (FNT - 1);
            float x = pp_s[pi] + q_s[n0 + nt];
            x = x > 0.0f ? x : LEAKY * x;
            w_s[pi][nt] = __expf(x - m_s[pi]);
        }
        __syncthreads();
        const float* drow = disease + (size_t)n0 * D_TOT + d2 * 4;
        #pragma unroll 4
        for (int nt = 0; nt < FNT; ++nt) {
            float4 dv = *reinterpret_cast<const float4*>(drow + (size_t)nt * D_TOT);
            float w0 = w_s[p0][nt];
            float w1 = w_s[p1][nt];
            acc0.x += w0 * dv.x; acc0.y += w0 * dv.y; acc0.z += w0 * dv.z; acc0.w += w0 * dv.w;
            acc1.x += w1 * dv.x; acc1.y += w1 * dv.y; acc1.z += w1 * dv.z; acc1.w += w1 * dv.w;
        }
    }
    const float inv0 = 1.0f / S_s[p0];
    const float inv1 = 1.0f / S_s[p1];
    {
        size_t off = (size_t)(b0 + p0) * D_TOT + d2 * 4;
        float4 pf = *reinterpret_cast<const float4*>(patient + off);
        float4 o;
        o.x = pf.x + acc0.x * inv0; o.y = pf.y + acc0.y * inv0;
        o.z = pf.z + acc0.z * inv0; o.w = pf.w + acc0.w * inv0;
        *reinterpret_cast<float4*>(reinterpret_cast<float*>(out) + off) = o;
    }
    {
        size_t off = (size_t)(b0 + p1) * D_TOT + d2 * 4;
        float4 pf = *reinterpret_cast<const float4*>(patient + off);
        float4 o;
        o.x = pf.x + acc1.x * inv1; o.y = pf.y + acc1.y * inv1;
        o.z = pf.z + acc1.z * inv1; o.w = pf.w + acc1.w * inv1;
        *reinterpret_cast<float4*>(reinterpret_cast<float*>(out) + off) = o;
    }
}

extern "C" void kernel_launch(void* const* d_in, const int* in_sizes, int n_in,
                              void* d_out, int out_size, void* d_ws, size_t ws_size,
                              hipStream_t stream) {
    const float* patient = (const float*)d_in[0];   // 8192 x 128
    const float* disease = (const float*)d_in[1];   // 2048 x 128
    const float* ak      = (const float*)d_in[2];   // 256
    float* out = (float*)d_out;

    const size_t need_fast = (size_t)512 * 1024 + 8192;   // DnTf (512KB) + q (8KB)
    if (ws_size >= need_fast) {
        uint4* DnTf = (uint4*)d_ws;                          // 128 kt x 4 ct x 64 uint4 = 512KB
        float* q    = (float*)((char*)d_ws + 512 * 1024);    // 2048 f32
        prep_kernel<<<N_TOT / 32, 256, 0, stream>>>(disease, ak, q, DnTf);
        gat_mfma32<<<B_TOT / BM, 1024, 0, stream>>>(patient, ak, q, DnTf, out);
    } else {
        float* p = (float*)d_ws;          // 8192 f32
        float* q = p + B_TOT;             // 2048 f32
        pq_fb<<<(B_TOT + N_TOT) / 4, 256, 0, stream>>>(patient, disease, ak, p, q);
        gat_fb<<<B_TOT / FBP, 256, 0, stream>>>(patient, disease, p, q, out);
    }
}